// Round 25
// baseline (193.663 us; speedup 1.0000x reference)
//
#include <hip/hip_runtime.h>

typedef float f4v __attribute__((ext_vector_type(4)));
typedef _Float16 h8 __attribute__((ext_vector_type(8)));
typedef _Float16 h4 __attribute__((ext_vector_type(4)));
typedef _Float16 h2 __attribute__((ext_vector_type(2)));
typedef __fp16 f16x2 __attribute__((ext_vector_type(2)));

// Problem constants
// C=192, NH=8, DH=24, window 6x8x8 -> N=384 tokens, D/H/W = 24/64/64 -> 256 windows
// shift (3,4,4). Spatial stride per channel = 24*64*64 = 98304.
// Staging layout (f16): [head][win][n][24]  -> slab (head,win) = 384*24 = 9216 elems.

__device__ __forceinline__ float fast_exp2(float x) {
#if __has_builtin(__builtin_amdgcn_exp2f)
    return __builtin_amdgcn_exp2f(x);
#else
    return exp2f(x);
#endif
}
__device__ __forceinline__ float fast_rcp(float x) {
#if __has_builtin(__builtin_amdgcn_rcpf)
    return __builtin_amdgcn_rcpf(x);
#else
    return 1.0f / x;
#endif
}

// region slot for token n (3-bit: d,h,w boundary crossing), block-uniform wi/hi/wj
__device__ __forceinline__ int region_slot(int n, int wi, int hi, int wj) {
    int s = 0;
    if (wi == 3 && (n >> 6) >= 3) s += 4;
    if (hi == 7 && ((n >> 3) & 7) >= 4) s += 2;
    if (wj == 7 && (n & 7) >= 4) s += 1;
    return s;
}

// ---------------------------------------------------------------------------
// Kernel 1 (r25): persistent dbuf LN with CORRECT prefetch placement.
// r24's prefetch sat BEFORE a __syncthreads -> compiler's mandatory
// s_waitcnt vmcnt(0) at the barrier drained it (full stall, zero overlap) —
// the experiment never ran. Fix: issue next slice's 12 loads AFTER the
// second barrier, inside the phase-3 region; their waits defer to first use
// (next iteration's phase 1b, pre-barrier) -> reads overlap normalize+write.
// No keep-alive asm / sched_barrier (those would force an in-region wait).
// sgam reload moved into the phase-2 region (first sync guards prev phase 3).
// ---------------------------------------------------------------------------
__global__ __launch_bounds__(256) void ln_stage_kernel(
    const float* __restrict__ q, const float* __restrict__ k, const float* __restrict__ v,
    const float* __restrict__ nqw, const float* __restrict__ nqb,
    const float* __restrict__ nkw, const float* __restrict__ nkb,
    _Float16* __restrict__ Qs, _Float16* __restrict__ Ks, _Float16* __restrict__ Vs)
{
    const int tid = threadIdx.x;
    const int bid = blockIdx.x;      // 0..511

    __shared__ __attribute__((aligned(16))) _Float16 tile[2][192][70];
    __shared__ __attribute__((aligned(16))) float psum4[4][64];
    __shared__ __attribute__((aligned(16))) float psq4[4][64];
    __shared__ float smean[64];
    __shared__ float srstd[64];
    __shared__ float sgam[192];
    __shared__ float sbet[192];

    const int lane = tid & 63;
    const int wid = tid >> 6;
    const int c0 = tid >> 4;           // 0..15
    const int col = (tid & 15) << 2;   // 0..60
    const float qscale = 0.20412414523193154f * 1.44269504088896340f;

    // prologue: tensor 0 norm params + slice 0 loads
    if (tid < 192) { sgam[tid] = nqw[tid]; sbet[tid] = nqb[tid]; }
    f4v xr[12];
    {
        const int d = bid >> 6, h = bid & 63;
        const float* base = q + (size_t)d * 4096 + (size_t)h * 64 + col;
        #pragma unroll
        for (int r = 0; r < 12; ++r)
            xr[r] = *(const f4v*)(base + (size_t)(r * 16 + c0) * 98304);
    }

    for (int i = 0; i < 9; ++i) {
        const int gs = i * 512 + bid;
        const int tensor = i / 3;                    // uniform per iteration
        const int s = gs - tensor * 1536;
        const int d = s >> 6, h = s & 63;
        const int cur = i & 1;
        _Float16* dst = (tensor == 0) ? Qs : (tensor == 1) ? Ks : Vs;
        const float scale = (tensor == 0) ? qscale : 1.0f;

        // phase 1b: partials (f32, from regs) + f16 tile[cur]
        // (vmcnt waits for the prefetched loads land HERE, at first use)
        {
            f4v s4 = {}, ss4 = {};
            #pragma unroll
            for (int r = 0; r < 12; ++r) {
                f4v x = xr[r];
                s4 += x;
                ss4 += x * x;
                h4 hx;
                hx[0] = (_Float16)x[0]; hx[1] = (_Float16)x[1];
                hx[2] = (_Float16)x[2]; hx[3] = (_Float16)x[3];
                *(h4*)&tile[cur][r * 16 + c0][col] = hx;
            }
            #pragma unroll
            for (int m = 0; m < 4; ++m) {
                s4[m] += __shfl_xor(s4[m], 16);  s4[m] += __shfl_xor(s4[m], 32);
                ss4[m] += __shfl_xor(ss4[m], 16); ss4[m] += __shfl_xor(ss4[m], 32);
            }
            if (lane < 16) {
                *(f4v*)&psum4[wid][lane * 4] = s4;
                *(f4v*)&psq4[wid][lane * 4] = ss4;
            }
        }
        __syncthreads();   // also guarantees: all waves finished prev phase 3

        // phase 2: per-token stats (+ norm-param reload at tensor boundaries,
        // safe here because the sync above ordered it after prev phase 3)
        if (i == 3 || i == 6) {
            if (tid < 192) { sgam[tid] = nkw[tid]; sbet[tid] = nkb[tid]; }
        }
        if (tid < 64) {
            float S = psum4[0][tid] + psum4[1][tid] + psum4[2][tid] + psum4[3][tid];
            float SS = psq4[0][tid] + psq4[1][tid] + psq4[2][tid] + psq4[3][tid];
            float mean = S * (1.0f / 192.0f);
            float var = SS * (1.0f / 192.0f) - mean * mean;
            smean[tid] = mean;
            srstd[tid] = rsqrtf(var + 1e-5f);
        }
        __syncthreads();

        // phase 3 region: FIRST issue next slice's loads (no barrier follows
        // until next iteration's phase-1b sync -> true overlap with writes)
        if (i < 8) {
            const int gs2 = gs + 512;
            const int t2 = (i + 1) / 3;
            const int s2 = gs2 - t2 * 1536;
            const int d2 = s2 >> 6, h2 = s2 & 63;
            const float* src2 = (t2 == 0) ? q : (t2 == 1) ? k : v;
            const float* base2 = src2 + (size_t)d2 * 4096 + (size_t)h2 * 64 + col;
            #pragma unroll
            for (int r = 0; r < 12; ++r)
                xr[r] = *(const f4v*)(base2 + (size_t)(r * 16 + c0) * 98304);
        }

        // normalize from tile[cur] + write f16 staging [head][win][n][24]
        {
            const int wpos = tid >> 2;   // 0..63 source w
            const int p = tid & 3;       // channel quarter = heads 2p, 2p+1
            const float mean = smean[wpos];
            const float rstd = srstd[wpos];
            int d_r = d + 21; if (d_r >= 24) d_r -= 24;
            int h_r = h + 60; if (h_r >= 64) h_r -= 64;
            int w_r = wpos + 60; if (w_r >= 64) w_r -= 64;
            const int wi = d_r / 6, td = d_r - wi * 6;
            const int hi = h_r >> 3, th = h_r & 7;
            const int wj = w_r >> 3, tw = w_r & 7;
            const int win = (wi * 8 + hi) * 8 + wj;
            const int n = (td * 8 + th) * 8 + tw;
            #pragma unroll
            for (int hh2 = 0; hh2 < 2; ++hh2) {
                const int head = p * 2 + hh2;
                _Float16* outp = dst + (size_t)(head * 256 + win) * 9216 + n * 24;
                #pragma unroll
                for (int cc = 0; cc < 3; ++cc) {
                    const int c = head * 24 + cc * 8;
                    h8 hv;
                    #pragma unroll
                    for (int j = 0; j < 8; ++j) {
                        float x = ((float)tile[cur][c + j][wpos] - mean) * rstd * sgam[c + j] + sbet[c + j];
                        hv[j] = (_Float16)(x * scale);
                    }
                    *(h8*)(outp + cc * 8) = hv;
                }
            }
        }
    }
}

// ---------------------------------------------------------------------------
// Kernel 2: proj_w f32 -> f16
// ---------------------------------------------------------------------------
__global__ __launch_bounds__(256) void wconv_kernel(const float* __restrict__ w,
                                                    _Float16* __restrict__ wb)
{
    int i = blockIdx.x * 256 + threadIdx.x;
    if (i < 192 * 192) wb[i] = (_Float16)w[i];
}

// ---------------------------------------------------------------------------
// attn epilogue: rowsum comes FREE from o1's duplicate lanes (l15>=8 read the
// ones-row) -> inv via one shfl per j. Wave-private Ob sub-tile; per-wave DS
// ordering + lgkmcnt fence (proven r4+).
// ---------------------------------------------------------------------------
__device__ __forceinline__ void attn_epilogue(
    f4v o0, f4v o1, _Float16* __restrict__ Op,
    _Float16* __restrict__ AOw, int q0, int lane, int l15, int g)
{
    #pragma unroll
    for (int j = 0; j < 4; ++j) {
        float rs = __shfl(o1[j], (g << 4) | 8);   // lane l15=8 of this g holds rowsum
        float inv = fast_rcp(rs);
        const int r = 4 * g + j;
        Op[r * 24 + l15] = (_Float16)(o0[j] * inv);
        if (l15 < 8) Op[r * 24 + 16 + l15] = (_Float16)(o1[j] * inv);
    }
    asm volatile("s_waitcnt lgkmcnt(0)" ::: "memory");
    // coalesced 768B burst: 48 lanes x 16B contiguous
    if (lane < 48) {
        h8 ov = *(const h8*)(Op + lane * 8);
        *(h8*)(AOw + (size_t)q0 * 24 + lane * 8) = ov;
    }
    asm volatile("" ::: "memory");
}

// ---------------------------------------------------------------------------
// Kernel 3: windowed attention, one block per (window, head). 8 WAVES (512t).
// r17 structure (unchanged): region-channel masking in the K=32 pad (one-hot
// * sqrt(40), cinit -46 -> masked p == 0 in f16); rowsum via ones-row in o1's
// duplicate lanes; 2+1 split fusion (pass A fuses qt{0,1}, pass B = qt2,
// pass-A AO stores hide under pass B). VGPR ~124 at (512,2) — do not perturb.
// ---------------------------------------------------------------------------
__global__ __launch_bounds__(512, 2) void attn_kernel(
    const _Float16* __restrict__ Qs, const _Float16* __restrict__ Ks,
    const _Float16* __restrict__ Vs, _Float16* __restrict__ AOs)
{
    const int win = blockIdx.x;
    const int head = blockIdx.y;
    const int tid = threadIdx.x;
    const int lane = tid & 63;
    const int wid = tid >> 6;        // 0..7
    const int l15 = lane & 15;
    const int g = lane >> 4;

    __shared__ __attribute__((aligned(16))) _Float16 Kh[384 * 36];      // [token][36]: dh0..23, onehot 24..31, pad
    __shared__ __attribute__((aligned(16))) _Float16 Vt[25 * 388];      // [dh][token pad388]; row 24 = ones
    __shared__ __attribute__((aligned(16))) _Float16 Ob[8][2][16 * 24]; // per-wave, qt-parity dbuf

    const int wi = win >> 6, hi = (win >> 3) & 7, wj = win & 7;

    const size_t slab = (size_t)(head * 256 + win) * 9216;
    const _Float16* Kw = Ks + slab;
    const _Float16* Vw = Vs + slab;
    const _Float16* Qw = Qs + slab;
    _Float16* AOw = AOs + slab;

    const _Float16 mreg = (_Float16)6.32455532f;   // sqrt(40)

    // ---- hoist this wave's 3 Q fragments; g==3 = one-hot(region(q)) * m ----
    h8 qreg[3];
    #pragma unroll
    for (int qt = 0; qt < 3; ++qt) {
        h8 z = {};
        if (g < 3) {
            z = *(const h8*)(Qw + (size_t)(wid * 48 + qt * 16 + l15) * 24 + g * 8);
        } else {
            int slot = region_slot(wid * 48 + qt * 16 + l15, wi, hi, wj);
            #pragma unroll
            for (int j = 0; j < 8; ++j) z[j] = (slot == j) ? mreg : (_Float16)0.f;
        }
        qreg[qt] = z;
    }

    // ---- stage K (36-wide rows + one-hot tails), V^T, ones-row ----
    {
        const h8* K8 = (const h8*)Kw;
        const h8* V8 = (const h8*)Vw;
        #pragma unroll
        for (int it = 0; it < 5; ++it) {
            int idx = it * 512 + tid;        // 0..2303 ; 0..1151 = K, 1152.. = V
            if (idx < 1152) {
                int n = idx / 3;
                int ch = idx - n * 3;
                *(h8*)(Kh + n * 36 + ch * 8) = K8[idx];
            } else if (idx < 2304) {
                int i = idx - 1152;          // flat h8 index in V slab
                int n = i / 3;               // token
                int ch = i - n * 3;          // 8-dh chunk
                h8 vv = V8[i];
                #pragma unroll
                for (int j = 0; j < 8; ++j) Vt[(ch * 8 + j) * 388 + n] = vv[j];
            }
        }
        if (tid < 384) {
            int slot = region_slot(tid, wi, hi, wj);
            h8 t;
            #pragma unroll
            for (int j = 0; j < 8; ++j) t[j] = (slot == j) ? mreg : (_Float16)0.f;
            *(h8*)(Kh + tid * 36 + 24) = t;
            Vt[24 * 388 + tid] = (_Float16)1.f;   // ones-row for rowsum
        }
    }
    __syncthreads();

    // lanes 0-7 of o1 -> dh 16-23; lanes 8-15 -> ones row (rowsum)
    const int v1row = (l15 < 8) ? (16 + l15) : 24;
    const int q0w = wid * 48;

    // ---- PASS A: fused qt0+qt1 mt loop (shared kf/v0/v1; 2 chains) ----
    f4v o0_0 = {}, o1_0 = {}, o0_1 = {}, o1_1 = {};
    #pragma unroll
    for (int mt = 0; mt < 24; ++mt) {
        h8 kf = *(const h8*)(Kh + (16 * mt + l15) * 36 + g * 8);
        h4 v0 = *(const h4*)(Vt + l15 * 388 + 16 * mt + 4 * g);
        h4 v1 = *(const h4*)(Vt + v1row * 388 + 16 * mt + 4 * g);
        const f4v cinit = {-46.f, -46.f, -46.f, -46.f};

        // qt0 chain
        {
            f4v s4 = __builtin_amdgcn_mfma_f32_16x16x32_f16(kf, qreg[0], cinit, 0, 0, 0);
            float p0 = fast_exp2(s4[0]), p1 = fast_exp2(s4[1]);
            float p2 = fast_exp2(s4[2]), p3 = fast_exp2(s4[3]);
            union { f16x2 gp[2]; h4 v; } pu;
            pu.gp[0] = __builtin_amdgcn_cvt_pkrtz(p0, p1);
            pu.gp[1] = __builtin_amdgcn_cvt_pkrtz(p2, p3);
            o0_0 = __builtin_amdgcn_mfma_f32_16x16x16f16(pu.v, v0, o0_0, 0, 0, 0);
            o1_0 = __builtin_amdgcn_mfma_f32_16x16x16f16(pu.v, v1, o1_0, 0, 0, 0);
        }
        // qt1 chain
        {
            f4v s4 = __builtin_amdgcn_mfma_f32_16x16x32_f16(kf, qreg[1], cinit, 0, 0, 0);
            float p0 = fast_exp2(s4[0]), p1 = fast_exp2(s4[1]);
            float p2 = fast_exp2(s4[2]), p3 = fast_exp2(s4[3]);
            union { f16x2 gp[2]; h4 v; } pu;
            pu.gp[0] = __builtin_amdgcn_cvt_pkrtz(p0, p1);
            pu.gp[1] = __builtin_amdgcn_cvt_pkrtz(p2, p3);
            o0_1 = __builtin_amdgcn_mfma_f32_16x16x16f16(pu.v, v0, o0_1, 0, 0, 0);
            o1_1 = __builtin_amdgcn_mfma_f32_16x16x16f16(pu.v, v1, o1_1, 0, 0, 0);
        }
    }

    // pass-A epilogues (AO stores issue now; latency hides under pass B)
    attn_epilogue(o0_0, o1_0, Ob[wid][0], AOw, q0w,      lane, l15, g);
    attn_epilogue(o0_1, o1_1, Ob[wid][1], AOw, q0w + 16, lane, l15, g);

    // ---- PASS B: qt2 alone (a/b acc split for dep-breaking) ----
    f4v o0a = {}, o0b = {}, o1a = {}, o1b = {};
    #pragma unroll
    for (int mt = 0; mt < 24; ++mt) {
        h8 kf = *(const h8*)(Kh + (16 * mt + l15) * 36 + g * 8);
        h4 v0 = *(const h4*)(Vt + l15 * 388 + 16 * mt + 4 * g);
        h4 v1 = *(const h4*)(Vt + v1row * 388 + 16 * mt + 4 * g);
        const f4v cinit = {-46.f, -46.f, -46.f, -46.f};
        f4v s4 = __builtin_amdgcn_mfma_f32_16x16x32_f16(kf, qreg[2], cinit, 0, 0, 0);
        float p0 = fast_exp2(s4[0]), p1 = fast_exp2(s4[1]);
        float p2 = fast_exp2(s4[2]), p3 = fast_exp2(s4[3]);
        union { f16x2 gp[2]; h4 v; } pu;
        pu.gp[0] = __builtin_amdgcn_cvt_pkrtz(p0, p1);
        pu.gp[1] = __builtin_amdgcn_cvt_pkrtz(p2, p3);
        if (mt & 1) {
            o0b = __builtin_amdgcn_mfma_f32_16x16x16f16(pu.v, v0, o0b, 0, 0, 0);
            o1b = __builtin_amdgcn_mfma_f32_16x16x16f16(pu.v, v1, o1b, 0, 0, 0);
        } else {
            o0a = __builtin_amdgcn_mfma_f32_16x16x16f16(pu.v, v0, o0a, 0, 0, 0);
            o1a = __builtin_amdgcn_mfma_f32_16x16x16f16(pu.v, v1, o1a, 0, 0, 0);
        }
    }
    attn_epilogue(o0a + o0b, o1a + o1b, Ob[wid][0], AOw, q0w + 32, lane, l15, g);
}

// ---------------------------------------------------------------------------
// Kernel 4: FUSED projection + window-reverse + roll-back + transpose (r23).
// Block = one (dd,hh) output row (grid 1536): gather rolled AO rows -> LDS,
// GEMM 64x192x192 (af from LDS regs, bf from Wb), acc -> tileT (aliased LDS)
// -> full 256B (c, 64w) row writes. LDS 52224B.
// ---------------------------------------------------------------------------
__global__ __launch_bounds__(256) void proj_wb_kernel(
    const _Float16* __restrict__ AOs, const _Float16* __restrict__ Wb,
    const float* __restrict__ bias, float* __restrict__ out)
{
    const int bid = blockIdx.x;        // dd*64 + hh
    const int dd = bid >> 6;
    const int hh = bid & 63;
    const int tid = threadIdx.x;
    const int lane = tid & 63, wid = tid >> 6;
    const int l15 = lane & 15, g = lane >> 4;

    __shared__ __attribute__((aligned(16))) unsigned char lmem[192 * 68 * 4]; // 52224B
    _Float16* Arows = (_Float16*)lmem;   // [64][200] f16 (25600B), dead after af load
    float* tileT = (float*)lmem;         // [192][68] f32, lives after barrier

    // inverse roll: window-space coords for this output row
    int d_r = dd + 21; if (d_r >= 24) d_r -= 24;
    int h_r = hh + 60; if (h_r >= 64) h_r -= 64;
    const int wi = d_r / 6, td = d_r - wi * 6;
    const int hi = h_r >> 3, th = h_r & 7;
    const int winbase = (wi * 8 + hi) * 8;
    const int nbase = (td * 8 + th) * 8;

    // 1. gather AO rows: 1536 h8 chunks (64 tokens x 24), 6 per thread
    #pragma unroll
    for (int it = 0; it < 6; ++it) {
        int idx = it * 256 + tid;
        int t = idx / 24;              // token (= output w)
        int ch = idx - t * 24;         // 8-channel chunk 0..23
        int w_r = t + 60; if (w_r >= 64) w_r -= 64;
        int win = winbase + (w_r >> 3);
        int n = nbase + (w_r & 7);
        int head = ch / 3, sub = ch - 3 * head;
        h8 v = *(const h8*)(AOs + (size_t)(head * 256 + win) * 9216
                                + (size_t)n * 24 + sub * 8);
        *(h8*)(Arows + t * 200 + ch * 8) = v;
    }
    __syncthreads();

    // 2a. preload this wave's 6 A-fragments (tokens wid*16..+15) to REGISTERS
    h8 af[6];
    #pragma unroll
    for (int kk = 0; kk < 6; ++kk)
        af[kk] = *(const h8*)(Arows + (wid * 16 + l15) * 200 + kk * 32 + g * 8);
    __syncthreads();   // Arows dead; tileT may now overwrite lmem

    // 2b. GEMM: n-outer, kk-inner; lane (l15,g) j -> C[c=n*16+l15][tok=wid*16+4g+j]
    f4v acc[12];
    #pragma unroll
    for (int n = 0; n < 12; ++n) {
        f4v a = {};
        #pragma unroll
        for (int kk = 0; kk < 6; ++kk) {
            h8 bf = *(const h8*)(Wb + (size_t)(n * 16 + l15) * 192 + kk * 32 + g * 8);
            a = __builtin_amdgcn_mfma_f32_16x16x32_f16(af[kk], bf, a, 0, 0, 0);
        }
        acc[n] = a;
    }

    // 3a. bias + write tileT[c][tok] (pad 68 -> 16B-aligned f4v rows)
    #pragma unroll
    for (int n = 0; n < 12; ++n) {
        float b = bias[n * 16 + l15];
        f4v vv = acc[n];
        vv[0] += b; vv[1] += b; vv[2] += b; vv[3] += b;
        *(f4v*)(tileT + (n * 16 + l15) * 68 + wid * 16 + g * 4) = vv;
    }
    __syncthreads();

    // 3b. write out: full 256B (c, 64w) rows; 4 lanes cover 64B contiguous
    float* obase = out + (size_t)dd * 4096 + hh * 64;
    #pragma unroll
    for (int r = 0; r < 3; ++r) {
        const int c = r * 64 + (tid >> 2);
        float* orow = obase + (size_t)c * 98304;
        const float* trow = tileT + c * 68;
        #pragma unroll
        for (int q = 0; q < 4; ++q) {
            const int w0 = q * 16 + (tid & 3) * 4;
            f4v v = *(const f4v*)(trow + w0);
            *(f4v*)(orow + w0) = v;
        }
    }
}

// ---------------------------------------------------------------------------
extern "C" void kernel_launch(void* const* d_in, const int* in_sizes, int n_in,
                              void* d_out, int out_size, void* d_ws, size_t ws_size,
                              hipStream_t stream) {
    const float* q_map = (const float*)d_in[0];
    const float* k_map = (const float*)d_in[1];
    const float* v_map = (const float*)d_in[2];
    const float* nqw = (const float*)d_in[3];
    const float* nqb = (const float*)d_in[4];
    const float* nkw = (const float*)d_in[5];
    const float* nkb = (const float*)d_in[6];
    const float* pw = (const float*)d_in[7];
    const float* pb = (const float*)d_in[8];
    float* out = (float*)d_out;

    // workspace layout (f16): Qs, Ks, Vs, AOs each 8*256*384*24 = 18,874,368 elems
    _Float16* ws = (_Float16*)d_ws;
    const size_t BUF = (size_t)8 * 256 * 384 * 24;
    _Float16* Qs = ws;
    _Float16* Ks = ws + BUF;
    _Float16* Vs = ws + 2 * BUF;
    _Float16* AOs = ws + 3 * BUF;
    _Float16* Wb = ws + 4 * BUF;   // + 73728 B, total ~151 MB

    ln_stage_kernel<<<512, 256, 0, stream>>>(q_map, k_map, v_map,
                                             nqw, nqb, nkw, nkb, Qs, Ks, Vs);
    wconv_kernel<<<144, 256, 0, stream>>>(pw, Wb);
    attn_kernel<<<dim3(256, 8), 512, 0, stream>>>(Qs, Ks, Vs, AOs);
    proj_wb_kernel<<<1536, 256, 0, stream>>>(AOs, Wb, pb, out);
}